// Round 1
// baseline (295.667 us; speedup 1.0000x reference)
//
#include <hip/hip_runtime.h>
#include <hip/hip_bf16.h>

typedef __attribute__((ext_vector_type(4))) float f32x4;
typedef __attribute__((ext_vector_type(8))) short bf16x8;

#define NPART 8192
#define DDIM 64
#define PDIM 32
#define MSTEPS 50
#define HDIM 512
#define W1T_LD 72   // padded leading dim (shorts) for W1t and A-tile
#define H_LD 520    // padded leading dim (shorts) for h-tile

__device__ __forceinline__ short f2bf(float f) {
  unsigned u = __builtin_bit_cast(unsigned, f);
  u = (u + 0x7fffu + ((u >> 16) & 1u)) >> 16;
  return (short)u;
}

__device__ __forceinline__ float fast_tanh(float xv) {
  float t = __expf(2.0f * xv);
  return 1.0f - 2.0f * __builtin_amdgcn_rcpf(t + 1.0f);
}

// One block = 32 particles for all 50 steps. 512 threads = 8 waves.
// GEMM1 (h = X @ W1[1:65]): wave w owns h-cols [64w, 64w+64), both 16-row m-tiles.
// GEMM2 (Z = h @ W2): wave w owns tile (mt = w>>2, nt = w&3) of the 32x64 Z.
__global__ __launch_bounds__(512) void sde_kernel(
    const float* __restrict__ X0, const float* __restrict__ V0,
    const float* __restrict__ Y, const float* __restrict__ theta,
    const float* __restrict__ W1, const float* __restrict__ b1,
    const float* __restrict__ W2, const float* __restrict__ b2,
    const float* __restrict__ noise, const int* __restrict__ obs_index,
    float* __restrict__ out) {
  __shared__ __align__(16) short lds_w1t[HDIM * W1T_LD];  // W1t[n][k] = W1[1+k][n], k<64
  __shared__ __align__(16) short lds_a[32 * W1T_LD];      // A[m][k] = X bf16
  __shared__ __align__(16) short lds_h[32 * H_LD];        // h[m][k]
  __shared__ float lds_vp[32 * 4];
  __shared__ float lds_v[32];

  const int tid = threadIdx.x;
  const int w = tid >> 6;
  const int lane = tid & 63;
  const int c = lane & 15;
  const int g = lane >> 4;
  const int pb = blockIdx.x * 32;

  const float dt = 0.02f;
  const float sqdt = sqrtf(dt);

  // ---- stage W1t (transposed X-part of W1) ----
  {
    const int n = tid;  // 0..511, one row per thread
    const float* src = W1 + 512 + n;  // W1[(1+k)*512 + n]
    #pragma unroll
    for (int k2 = 0; k2 < 32; ++k2) {
      float a0 = src[(2 * k2) * 512];
      float a1 = src[(2 * k2 + 1) * 512];
      unsigned pk = (unsigned)(unsigned short)f2bf(a0) |
                    ((unsigned)(unsigned short)f2bf(a1) << 16);
      *reinterpret_cast<int*>(&lds_w1t[n * W1T_LD + 2 * k2]) = pk;
    }
  }

  // ---- stage Yt (f32) into lds_h scratch ----
  {
    float* yt = reinterpret_cast<float*>(lds_h);
    const int obs = obs_index[0];
    for (int i = tid; i < 32 * PDIM; i += 512) {
      int m = i >> 5, p = i & 31;
      yt[i] = Y[((size_t)(pb + m) * 1 + obs) * PDIM + p];  // T == 1
    }
  }

  // ---- X state (register, GEMM2-D layout), A-tile, V ----
  const int mtw = w >> 2, ntw = w & 3;
  float x[4];
  #pragma unroll
  for (int r = 0; r < 4; ++r) {
    int m = 16 * mtw + 4 * g + r;
    x[r] = X0[(size_t)(pb + m) * DDIM + 16 * ntw + c];
    lds_a[m * W1T_LD + 16 * ntw + c] = f2bf(x[r]);
  }
  if (tid < 32) lds_v[tid] = V0[pb + tid];

  __syncthreads();

  // ---- C_Y = Yt @ W1[65:97] + b1 in GEMM1-acc layout; rv0 = W1[0][:] ----
  float cy[2][4][4];
  float rv0[4];
  int nj[4];
  #pragma unroll
  for (int j = 0; j < 4; ++j) {
    nj[j] = 64 * w + 16 * j + c;
    rv0[j] = W1[nj[j]];
    float bv = b1[nj[j]];
    #pragma unroll
    for (int mt = 0; mt < 2; ++mt)
      #pragma unroll
      for (int r = 0; r < 4; ++r) cy[mt][j][r] = bv;
  }
  {
    const float* yt = reinterpret_cast<const float*>(lds_h);
    for (int p = 0; p < PDIM; ++p) {
      float wv[4];
      #pragma unroll
      for (int j = 0; j < 4; ++j) wv[j] = W1[(65 + p) * 512 + nj[j]];
      #pragma unroll
      for (int mt = 0; mt < 2; ++mt) {
        #pragma unroll
        for (int r = 0; r < 4; ++r) {
          float yv = yt[(16 * mt + 4 * g + r) * PDIM + p];
          #pragma unroll
          for (int j = 0; j < 4; ++j) cy[mt][j][r] = fmaf(yv, wv[j], cy[mt][j][r]);
        }
      }
    }
  }

  // ---- W2 B-fragments in registers (wave's nt column block) ----
  bf16x8 w2f[16];
  #pragma unroll
  for (int kt = 0; kt < 16; ++kt) {
    #pragma unroll
    for (int i = 0; i < 8; ++i) {
      w2f[kt][i] = f2bf(W2[(size_t)(32 * kt + 8 * g + i) * DDIM + 16 * ntw + c]);
    }
  }
  const float thv = theta[16 * ntw + c];
  const float b2v = b2[16 * ntw + c];

  __syncthreads();  // done with yt scratch in lds_h

  for (int st = 0; st < MSTEPS; ++st) {
    const float s = st * dt;

    // prefetch this step's noise (consumed after GEMM2)
    float wm[4];
    const float* np_ = noise + ((size_t)st * NPART + pb) * DDIM + 16 * ntw + c;
    #pragma unroll
    for (int r = 0; r < 4; ++r) wm[r] = np_[(size_t)(16 * mtw + 4 * g + r) * DDIM];

    // ---- GEMM1: h_pre = X @ W1[1:65] ----
    f32x4 acc1[2][4];
    #pragma unroll
    for (int mt = 0; mt < 2; ++mt)
      #pragma unroll
      for (int j = 0; j < 4; ++j) acc1[mt][j] = (f32x4){0.f, 0.f, 0.f, 0.f};

    bf16x8 af[2][2], bfr[4][2];
    #pragma unroll
    for (int mt = 0; mt < 2; ++mt)
      #pragma unroll
      for (int kt = 0; kt < 2; ++kt)
        af[mt][kt] = *reinterpret_cast<const bf16x8*>(
            &lds_a[(16 * mt + c) * W1T_LD + 32 * kt + 8 * g]);
    #pragma unroll
    for (int j = 0; j < 4; ++j)
      #pragma unroll
      for (int kt = 0; kt < 2; ++kt)
        bfr[j][kt] = *reinterpret_cast<const bf16x8*>(
            &lds_w1t[nj[j] * W1T_LD + 32 * kt + 8 * g]);

    #pragma unroll
    for (int mt = 0; mt < 2; ++mt)
      #pragma unroll
      for (int j = 0; j < 4; ++j)
        #pragma unroll
        for (int kt = 0; kt < 2; ++kt)
          acc1[mt][j] = __builtin_amdgcn_mfma_f32_16x16x32_bf16(
              af[mt][kt], bfr[j][kt], acc1[mt][j], 0, 0, 0);

    // ---- epilogue: tanh(acc + C_Y + s*W1[0]) -> lds_h bf16 ----
    #pragma unroll
    for (int mt = 0; mt < 2; ++mt)
      #pragma unroll
      for (int j = 0; j < 4; ++j)
        #pragma unroll
        for (int r = 0; r < 4; ++r) {
          float pre = acc1[mt][j][r] + cy[mt][j][r] + s * rv0[j];
          float h = fast_tanh(pre);
          lds_h[(16 * mt + 4 * g + r) * H_LD + nj[j]] = f2bf(h);
        }

    __syncthreads();  // B1: h complete; safe to write lds_a after this

    // ---- GEMM2: Z = h @ W2 + b2 (wave tile mtw,ntw) ----
    f32x4 acc2 = (f32x4){b2v, b2v, b2v, b2v};
    #pragma unroll
    for (int kt = 0; kt < 16; ++kt) {
      bf16x8 ha = *reinterpret_cast<const bf16x8*>(
          &lds_h[(16 * mtw + c) * H_LD + 32 * kt + 8 * g]);
      acc2 = __builtin_amdgcn_mfma_f32_16x16x32_bf16(ha, w2f[kt], acc2, 0, 0, 0);
    }

    // ---- per-element updates ----
    float vr[4];
    #pragma unroll
    for (int r = 0; r < 4; ++r) {
      float z = acc2[r];
      float wmr = sqdt * wm[r];
      vr[r] = z * (wmr - 0.5f * dt * z);        // z*wm + dt*(-0.5 z^2)
      x[r] = x[r] + dt * (thv - x[r] - z) + wmr;
    }
    // reduce over the 16 d-lanes of this wave's column block
    #pragma unroll
    for (int mask = 1; mask <= 8; mask <<= 1)
      #pragma unroll
      for (int r = 0; r < 4; ++r) vr[r] += __shfl_xor(vr[r], mask);
    if (c == 0) {
      #pragma unroll
      for (int r = 0; r < 4; ++r)
        lds_vp[(16 * mtw + 4 * g + r) * 4 + ntw] = vr[r];
    }
    // write new X into A-tile for next step's GEMM1
    #pragma unroll
    for (int r = 0; r < 4; ++r)
      lds_a[(16 * mtw + 4 * g + r) * W1T_LD + 16 * ntw + c] = f2bf(x[r]);

    __syncthreads();  // B2: vpart + A-tile ready

    if (tid < 32) {
      lds_v[tid] += lds_vp[tid * 4] + lds_vp[tid * 4 + 1] +
                    lds_vp[tid * 4 + 2] + lds_vp[tid * 4 + 3];
    }
  }

  // ---- output: X (N x 64 f32), then V (N f32) ----
  #pragma unroll
  for (int r = 0; r < 4; ++r)
    out[(size_t)(pb + 16 * mtw + 4 * g + r) * DDIM + 16 * ntw + c] = x[r];
  if (tid < 32) out[(size_t)NPART * DDIM + pb + tid] = lds_v[tid];
}

extern "C" void kernel_launch(void* const* d_in, const int* in_sizes, int n_in,
                              void* d_out, int out_size, void* d_ws, size_t ws_size,
                              hipStream_t stream) {
  sde_kernel<<<256, 512, 0, stream>>>(
      (const float*)d_in[0], (const float*)d_in[1], (const float*)d_in[2],
      (const float*)d_in[3], (const float*)d_in[4], (const float*)d_in[5],
      (const float*)d_in[6], (const float*)d_in[7], (const float*)d_in[8],
      (const int*)d_in[9], (float*)d_out);
}

// Round 2
// 272.461 us; speedup vs baseline: 1.0852x; 1.0852x over previous
//
#include <hip/hip_runtime.h>
#include <hip/hip_bf16.h>

typedef __attribute__((ext_vector_type(4))) float f32x4;
typedef __attribute__((ext_vector_type(8))) short bf16x8;

#define NPART 8192
#define DDIM 64
#define PDIM 32
#define MSTEPS 50
#define HDIM 512
#define A_LD 72    // shorts
#define H_LD 520   // shorts

__device__ __forceinline__ short f2bf(float f) {
  unsigned u = __builtin_bit_cast(unsigned, f);
  u = (u + 0x7fffu + ((u >> 16) & 1u)) >> 16;
  return (short)u;
}

__device__ __forceinline__ float fast_tanh(float xv) {
  float t = __expf(2.0f * xv);
  return 1.0f - 2.0f * __builtin_amdgcn_rcpf(t + 1.0f);
}

// lane-pair (c, c+1) pack: even lane returns bf16(own)|bf16(neighbor)<<16
__device__ __forceinline__ unsigned pack_pair(float own) {
  int oi = __builtin_amdgcn_mov_dpp(__builtin_bit_cast(int, own),
                                    0xB1 /*quad_perm(1,0,3,2)*/, 0xF, 0xF, true);
  float other = __builtin_bit_cast(float, oi);
  unsigned out;
  asm("v_cvt_pk_bf16_f32 %0, %1, %2" : "=v"(out) : "v"(own), "v"(other));
  return out;  // valid on even lanes (S0=own=col c, S1=neighbor=col c+1)
}

// 1024 threads = 16 waves, 32 particles/block, grid 256 (1 block/CU, 16 waves/CU).
// GEMM1 (h = [X]@W1x, K=64): wave w owns h-cols [32w, 32w+32), e in {0,1} -> 16-col tiles.
// GEMM2 (Z = h@W2, K=512 split): wave role (mtw = w>>3, ntw = (w>>1)&3, kh = w&1);
//   each (mtw,ntw,kh) wave does K-half 256*kh; kh=1 ships partial via LDS to kh=0.
__global__ __launch_bounds__(1024) void sde_kernel(
    const float* __restrict__ X0, const float* __restrict__ V0,
    const float* __restrict__ Y, const float* __restrict__ theta,
    const float* __restrict__ W1, const float* __restrict__ b1,
    const float* __restrict__ W2, const float* __restrict__ b2,
    const float* __restrict__ noise, const int* __restrict__ obs_index,
    float* __restrict__ out) {
  __shared__ __align__(16) short lds_h[32 * H_LD];   // 33.3 KB
  __shared__ __align__(16) short lds_a[32 * A_LD];   // 4.6 KB
  __shared__ __align__(16) float lds_p[8 * 64 * 4];  // 8 KB: Yt scratch / Z-partials / V-partials

  const int tid = threadIdx.x;
  const int w = tid >> 6;
  const int lane = tid & 63;
  const int c = lane & 15;
  const int g = lane >> 4;
  const int pb = blockIdx.x * 32;
  const int kh = w & 1, ntw = (w >> 1) & 3, mtw = w >> 3;

  const float dt = 0.02f;
  const float sqdt = sqrtf(dt);

  // ---- stage Yt (f32) into lds_p scratch ----
  {
    int m = tid >> 5, p = tid & 31;
    lds_p[m * PDIM + p] =
        Y[(size_t)(pb + m) * PDIM + (size_t)obs_index[0] * PDIM + p];
  }

  // ---- X state (kh0 waves, GEMM2-D layout) + initial A-tile ----
  float x[4] = {0.f, 0.f, 0.f, 0.f};
  if (kh == 0) {
    #pragma unroll
    for (int r = 0; r < 4; ++r) {
      int m = 16 * mtw + 4 * g + r;
      x[r] = X0[(size_t)(pb + m) * DDIM + 16 * ntw + c];
      lds_a[m * A_LD + 16 * ntw + c] = f2bf(x[r]);
    }
  }
  __syncthreads();

  // ---- cy = Yt @ W1[65:97] + b1, in GEMM1-acc layout ----
  const int nj0 = 32 * w + c;
  float cy[2][2][4];
  float rv0[2] = {W1[nj0], W1[nj0 + 16]};
  {
    float bv0 = b1[nj0], bv1 = b1[nj0 + 16];
    #pragma unroll
    for (int mt = 0; mt < 2; ++mt)
      #pragma unroll
      for (int r = 0; r < 4; ++r) { cy[mt][0][r] = bv0; cy[mt][1][r] = bv1; }
    for (int p = 0; p < PDIM; ++p) {
      float wv0 = W1[(size_t)(65 + p) * HDIM + nj0];
      float wv1 = W1[(size_t)(65 + p) * HDIM + nj0 + 16];
      #pragma unroll
      for (int mt = 0; mt < 2; ++mt)
        #pragma unroll
        for (int r = 0; r < 4; ++r) {
          float yv = lds_p[(16 * mt + 4 * g + r) * PDIM + p];
          cy[mt][0][r] = fmaf(yv, wv0, cy[mt][0][r]);
          cy[mt][1][r] = fmaf(yv, wv1, cy[mt][1][r]);
        }
    }
  }

  // ---- W1 X-part B-fragments in registers (loop-invariant) ----
  bf16x8 bfr[2][2];
  #pragma unroll
  for (int e = 0; e < 2; ++e)
    #pragma unroll
    for (int kt = 0; kt < 2; ++kt)
      #pragma unroll
      for (int i = 0; i < 8; ++i)
        bfr[e][kt][i] =
            f2bf(W1[(size_t)(1 + 32 * kt + 8 * g + i) * HDIM + nj0 + 16 * e]);

  // ---- W2 B-fragments (this wave's K-half, 16-col slice) ----
  bf16x8 w2f[8];
  #pragma unroll
  for (int kt = 0; kt < 8; ++kt)
    #pragma unroll
    for (int i = 0; i < 8; ++i)
      w2f[kt][i] =
          f2bf(W2[(size_t)(256 * kh + 32 * kt + 8 * g + i) * DDIM + 16 * ntw + c]);

  const float thv = theta[16 * ntw + c];
  const float b2v = b2[16 * ntw + c];
  float vacc[4] = {0.f, 0.f, 0.f, 0.f};

  __syncthreads();  // Yt scratch free; A-tile ready

  for (int st = 0; st < MSTEPS; ++st) {
    const float s = st * dt;

    // prefetch this step's noise (kh0 only; consumed after GEMM2)
    float wm[4];
    if (kh == 0) {
      const float* np_ =
          noise + ((size_t)st * NPART + pb + 16 * mtw + 4 * g) * DDIM + 16 * ntw + c;
      #pragma unroll
      for (int r = 0; r < 4; ++r) wm[r] = np_[(size_t)r * DDIM];
    }

    // ---- GEMM1 + tanh epilogue -> lds_h ----
    #pragma unroll
    for (int mt = 0; mt < 2; ++mt) {
      const int abase = (16 * mt + c) * A_LD + 8 * g;
      bf16x8 af0 = *reinterpret_cast<const bf16x8*>(&lds_a[abase]);
      bf16x8 af1 = *reinterpret_cast<const bf16x8*>(&lds_a[abase + 32]);
      #pragma unroll
      for (int e = 0; e < 2; ++e) {
        f32x4 acc = {0.f, 0.f, 0.f, 0.f};
        acc = __builtin_amdgcn_mfma_f32_16x16x32_bf16(af0, bfr[e][0], acc, 0, 0, 0);
        acc = __builtin_amdgcn_mfma_f32_16x16x32_bf16(af1, bfr[e][1], acc, 0, 0, 0);
        float sb = s * rv0[e];
        unsigned pk[4];
        #pragma unroll
        for (int r = 0; r < 4; ++r)
          pk[r] = pack_pair(fast_tanh(acc[r] + cy[mt][e][r] + sb));
        if (!(lane & 1)) {
          #pragma unroll
          for (int r = 0; r < 4; ++r)
            *reinterpret_cast<unsigned*>(
                &lds_h[(16 * mt + 4 * g + r) * H_LD + nj0 + 16 * e]) = pk[r];
        }
      }
    }

    __syncthreads();  // B1: h ready

    // ---- GEMM2 K-half ----
    f32x4 acc2 = {0.f, 0.f, 0.f, 0.f};
    {
      const int hbase = (16 * mtw + c) * H_LD + 256 * kh + 8 * g;
      #pragma unroll
      for (int kt = 0; kt < 8; ++kt)
        acc2 = __builtin_amdgcn_mfma_f32_16x16x32_bf16(
            *reinterpret_cast<const bf16x8*>(&lds_h[hbase + 32 * kt]), w2f[kt],
            acc2, 0, 0, 0);
    }
    float* pslot = &lds_p[((mtw * 4 + ntw) * 64 + lane) * 4];
    if (kh) *reinterpret_cast<f32x4*>(pslot) = acc2;

    __syncthreads();  // B2: partials ready

    if (!kh) {
      f32x4 part = *reinterpret_cast<const f32x4*>(pslot);
      unsigned apk[4];
      #pragma unroll
      for (int r = 0; r < 4; ++r) {
        float z = acc2[r] + part[r] + b2v;
        float wmr = sqdt * wm[r];
        vacc[r] = fmaf(z, wmr - 0.5f * dt * z, vacc[r]);
        x[r] = x[r] + dt * (thv - x[r] - z) + wmr;
        apk[r] = pack_pair(x[r]);
      }
      if (!(lane & 1)) {
        #pragma unroll
        for (int r = 0; r < 4; ++r)
          *reinterpret_cast<unsigned*>(
              &lds_a[(16 * mtw + 4 * g + r) * A_LD + 16 * ntw + c]) = apk[r];
      }
    }

    __syncthreads();  // B3: A-tile ready for next step
  }

  // ---- output: X (N x 64 f32), then V (N f32) ----
  if (!kh) {
    #pragma unroll
    for (int r = 0; r < 4; ++r)
      out[(size_t)(pb + 16 * mtw + 4 * g + r) * DDIM + 16 * ntw + c] = x[r];
    #pragma unroll
    for (int mask = 1; mask <= 8; mask <<= 1)
      #pragma unroll
      for (int r = 0; r < 4; ++r) vacc[r] += __shfl_xor(vacc[r], mask);
    if (c == 0) {
      #pragma unroll
      for (int r = 0; r < 4; ++r)
        lds_p[(16 * mtw + 4 * g + r) * 4 + ntw] = vacc[r];
    }
  }
  __syncthreads();
  if (tid < 32)
    out[(size_t)NPART * DDIM + pb + tid] =
        V0[pb + tid] + lds_p[tid * 4] + lds_p[tid * 4 + 1] +
        lds_p[tid * 4 + 2] + lds_p[tid * 4 + 3];
}

extern "C" void kernel_launch(void* const* d_in, const int* in_sizes, int n_in,
                              void* d_out, int out_size, void* d_ws, size_t ws_size,
                              hipStream_t stream) {
  sde_kernel<<<256, 1024, 0, stream>>>(
      (const float*)d_in[0], (const float*)d_in[1], (const float*)d_in[2],
      (const float*)d_in[3], (const float*)d_in[4], (const float*)d_in[5],
      (const float*)d_in[6], (const float*)d_in[7], (const float*)d_in[8],
      (const int*)d_in[9], (float*)d_out);
}